// Round 1
// baseline (4604.211 us; speedup 1.0000x reference)
//
#include <hip/hip_runtime.h>
#include <stdint.h>

// ---------------------------------------------------------------------------
// 3-layer packed-sequence LSTM, B=64 T=2048 D=40 H=164, FC->7. fp32 in/out.
//
// Staircase-pipelined launch chain (NO inter-block sync, cannot hang):
//   for i in 0..17:
//     kgemm(i): input projections gx_l(chunk i-l) via mfma_f32_16x16x32_f16
//     krec (i): recurrence blocks (l=0,chunk i), (l=1,chunk i-1), (l=2,chunk i-2)
//
// krec (NEW shape, 384 thr = 6 waves):
//   Gate re-pairing: lane (wave w, k=ln&31, half=ln>>5) owns h-element
//   j = 32w+k and computes TWO gate rows of that SAME element:
//     half 0 -> rows j (i-gate), j+164 (f-gate)
//     half 1 -> rows j+328 (g-gate), j+492 (o-gate)
//   => the 4 gates of element j live in lanes k and k+32 of ONE wave:
//      exchanged with 2x __shfl_xor(.,32), so there is no gates LDS
//      round-trip, no gates barrier, and the cell update runs in ALL
//      lanes in parallel (redundant across halves) instead of a 3-of-11
//      wave serial tail.
//   h is double-buffered in LDS (read buf p, write buf p^1) => exactly ONE
//   __syncthreads per timestep, race-free by construction.
//   Weights: 2 rows x 84 dwords = 168 VGPRs/lane; 6 waves/block, 1 block/CU
//   => fits the 256-VGPR file directly (no AGPR shuttling).
//   h broadcast stays the proven readlane->SGPR->v_dot2_f32_f16 path
//   (84 readlanes/wave/step, shared by both rows).
// ---------------------------------------------------------------------------

#define TT 2048
#define BB 64
#define GG 656   // 4*H
#define HH 164
#define CC 128   // chunk timesteps
#define NCH (TT/CC)   // 16

typedef _Float16 half2v __attribute__((ext_vector_type(2)));
typedef _Float16 half8  __attribute__((ext_vector_type(8)));
typedef float    f32x4  __attribute__((ext_vector_type(4)));

// ---- workspace layout (bytes) ----
#define SZ_W16_B   (3*GG*192*2)                 // f16 [3][656][192]
#define OFF_WIH_B  0
#define OFF_WHH_B  (SZ_W16_B)
#define OFF_GX_B   (2*SZ_W16_B)
#define SZ_GX_B    ((size_t)3*BB*CC*GG*2)       // f16 [3][64][128][656]
#define OFF_HR_B   (OFF_GX_B + SZ_GX_B)
#define SZ_HR_B    ((size_t)2*2*BB*CC*96*4)     // dwords [2 layers][2 slots][64][128][96]
#define OFF_SC_B   (OFF_HR_B + SZ_HR_B)
#define SZ_SC_B    (3*BB*HH*4)                  // f32 c-state
#define OFF_SH_B   (OFF_SC_B + SZ_SC_B)
#define SZ_SH_B    (3*BB*96*4)                  // dword h-state (f16 pairs)
#define WS_TOTAL_B (OFF_SH_B + SZ_SH_B)         // ~46.5 MB

__device__ __forceinline__ float dot2(uint32_t w, uint32_t h, float acc) {
#if __has_builtin(__builtin_amdgcn_fdot2)
  return __builtin_amdgcn_fdot2(__builtin_bit_cast(half2v, w),
                                __builtin_bit_cast(half2v, h), acc, false);
#else
  half2v a = __builtin_bit_cast(half2v, w);
  half2v b = __builtin_bit_cast(half2v, h);
  return acc + (float)a[0]*(float)b[0] + (float)a[1]*(float)b[1];
#endif
}

__device__ __forceinline__ float sigmf(float x) { return 1.0f/(1.0f + __expf(-x)); }
__device__ __forceinline__ float tanhf_(float x) { return 2.0f/(1.0f + __expf(-2.0f*x)) - 1.0f; }

// ---------------------------------------------------------------------------
// weight prep: fp32 -> f16, pad K to 192 halves (zeros), row-major [3][656][192]
// ---------------------------------------------------------------------------
__global__ void kprep_w(const float* wih0, const float* whh0,
                        const float* wih1, const float* whh1,
                        const float* wih2, const float* whh2,
                        _Float16* wih16, _Float16* whh16) {
  int i = threadIdx.x + blockIdx.x * blockDim.x;
  if (i >= 3*GG*192) return;
  int l = i / (GG*192);
  int r = i - l*(GG*192);
  int j = r / 192;
  int k = r - j*192;
  float vi = 0.f, vh = 0.f;
  if (l == 0) {
    if (k < 40) vi = wih0[j*40 + k];
    if (k < HH) vh = whh0[j*HH + k];
  } else if (l == 1) {
    if (k < HH) vi = wih1[j*HH + k];
    if (k < HH) vh = whh1[j*HH + k];
  } else {
    if (k < HH) vi = wih2[j*HH + k];
    if (k < HH) vh = whh2[j*HH + k];
  }
  wih16[i] = (_Float16)vi;
  whh16[i] = (_Float16)vh;
}

// ---------------------------------------------------------------------------
// input-projection GEMM for one chunk: gx[l][b][row 0..127][656] f16
//   layer 0: A = x (fp32, converted on the fly, K padded 40->64)
//   layer 1/2: A = h ring of previous layer (f16 pairs, K padded 164->192)
// grid 192 (= 3 layers x 64 batches), 256 threads (4 waves)
// ---------------------------------------------------------------------------
__launch_bounds__(256, 4)
__global__ void kgemm(int step, const int* lengths, const float* x,
                      const uint32_t* wihw, const uint32_t* hring,
                      uint16_t* gx) {
  const int l  = blockIdx.x >> 6;
  const int b  = blockIdx.x & 63;
  const int ch = step - l;
  if (ch < 0 || ch >= NCH) return;
  int len = lengths[b];
  if (len < 1) len = 1; if (len > TT) len = TT;
  if (ch*CC >= len) return;                    // whole chunk past this sequence
  const int tid  = threadIdx.x;
  const int lane = tid & 63, wv = tid >> 6;
  const int quad = lane >> 4, n15 = lane & 15;
  const int Kt = (l == 0) ? 2 : 6;
  uint16_t* gxo = gx + (size_t)(l*BB + b)*CC*GG;
  const uint32_t* hbs = (l > 0)
      ? hring + ((size_t)((l-1)*2 + (ch & 1))*BB + b)*CC*96 : (const uint32_t*)0;

  __shared__ __align__(16) uint32_t smem[3200];  // 32 rows x 100 dwords

  for (int st = 0; st < 4; ++st) {
    // ---- stage A-tile (32 timesteps x K halves) ----
    if (l == 0) {
      for (int idx = tid; idx < 32*32; idx += 256) {
        int row = idx >> 5, dw = idx & 31;
        int t = ch*CC + st*32 + row;
        uint32_t v = 0;
        if (dw < 20) {
          const float* xs = x + ((size_t)b*TT + t)*40 + dw*2;
          half2v p; p[0] = (_Float16)xs[0]; p[1] = (_Float16)xs[1];
          v = __builtin_bit_cast(uint32_t, p);
        }
        smem[row*100 + dw] = v;
      }
    } else {
      for (int idx = tid; idx < 32*96; idx += 256) {
        int row = idx / 96, dw = idx - row*96;
        smem[row*100 + dw] = hbs[(size_t)(st*32 + row)*96 + dw];
      }
    }
    __syncthreads();

    // ---- MFMA: [32 x K] @ W^T -> [32 x 656]; 4 waves over 41 N-tiles ----
    const half8* asrc = (const half8*)smem;     // row stride 25 half8
    for (int nt = wv; nt < 41; nt += 4) {
      int wrow = nt*16 + n15;
      const half8* bsrc = (const half8*)(wihw + (size_t)(l*GG + wrow)*96);
      f32x4 a0 = {0.f,0.f,0.f,0.f};
      f32x4 a1 = {0.f,0.f,0.f,0.f};
      for (int kk = 0; kk < Kt; ++kk) {
        half8 bf  = bsrc[kk*4 + quad];
        half8 af0 = asrc[ n15      *25 + kk*4 + quad];
        half8 af1 = asrc[(n15 + 16)*25 + kk*4 + quad];
        a0 = __builtin_amdgcn_mfma_f32_16x16x32_f16(af0, bf, a0, 0, 0, 0);
        a1 = __builtin_amdgcn_mfma_f32_16x16x32_f16(af1, bf, a1, 0, 0, 0);
      }
      #pragma unroll
      for (int r = 0; r < 4; ++r) {
        int row0 = st*32 + quad*4 + r;          // C/D: col=lane&15, row=quad*4+reg
        _Float16 h0 = (_Float16)a0[r];
        _Float16 h1 = (_Float16)a1[r];
        gxo[(size_t)row0*GG + wrow]        = __builtin_bit_cast(uint16_t, h0);
        gxo[(size_t)(row0 + 16)*GG + wrow] = __builtin_bit_cast(uint16_t, h1);
      }
    }
    __syncthreads();
  }
}

// ---------------------------------------------------------------------------
// recurrence for one chunk of one (layer, batch): 384 threads = 6 waves
// lane owns h-element j = 32*wave + (ln&31); half = ln>>5 picks (i,f)/(g,o)
// grid 192 (= 3 layers x 64 batches)
// ---------------------------------------------------------------------------
__launch_bounds__(384, 1)
__global__ void krec(int step, const int* lengths,
                     const float* b0, const float* b1, const float* b2,
                     const uint32_t* whhw, const uint16_t* gx,
                     uint32_t* hring, float* state_c, uint32_t* state_h) {
  const int l  = blockIdx.x >> 6;
  const int b  = blockIdx.x & 63;
  const int ch = step - l;
  if (ch < 0 || ch >= NCH) return;
  int len = lengths[b];
  if (len < 1) len = 1; if (len > TT) len = TT;
  const int t0 = ch*CC;
  if (t0 >= len) return;                        // frozen; state already final
  int t1 = t0 + CC; if (t1 > len) t1 = len;

  const int tid = threadIdx.x;
  const int wv  = tid >> 6;                     // 0..5
  const int ln  = tid & 63;
  const int hf  = ln >> 5;                      // 0: rows (i,f); 1: rows (g,o)
  const int k32 = ln & 31;
  const int jj  = wv*32 + k32;                  // 0..191 (164..191 idle-clamped)
  const int valid = (jj < HH);
  const int j  = valid ? jj : (HH - 1);
  const int rA = hf ? (j + 2*HH) : j;           // g : i
  const int rB = hf ? (j + 3*HH) : (j + HH);    // o : f

  __shared__ __align__(16) uint32_t hbuf[2][96]; // h as f16 pairs, double-buffered

  // W_hh rows rA, rB: 84 packed-f16-pair dwords each (K padded 164->168)
  uint4 wA4[21], wB4[21];
  {
    const uint4* a4 = (const uint4*)(whhw + (size_t)(l*GG + rA)*96);
    const uint4* c4 = (const uint4*)(whhw + (size_t)(l*GG + rB)*96);
    #pragma unroll
    for (int c = 0; c < 21; ++c) { wA4[c] = a4[c]; wB4[c] = c4[c]; }
  }
  const uint32_t* wA = (const uint32_t*)wA4;
  const uint32_t* wB = (const uint32_t*)wB4;
  const float* bp = (l == 0) ? b0 : ((l == 1) ? b1 : b2);
  const float biasA = bp[rA], biasB = bp[rB];

  float cst = 0.f;
  if (tid < 96) {
    uint32_t v0 = 0u;
    if (ch > 0) v0 = state_h[(l*BB + b)*96 + tid];
    hbuf[0][tid] = v0;
    hbuf[1][tid] = 0u;                          // pads (dw 82..95) must stay 0
  }
  if (ch > 0) cst = state_c[(l*BB + b)*HH + j];
  __syncthreads();

  const uint16_t* gxb = gx + (size_t)(l*BB + b)*CC*GG;
  uint32_t* hrb = (l < 2)
      ? hring + ((size_t)(l*2 + (ch & 1))*BB + b)*CC*96 : (uint32_t*)0;

  uint16_t gxA = gxb[rA];                       // row 0 of chunk
  uint16_t gxB = gxb[rB];
  int p = 0;

  for (int t = t0; t < t1; ++t) {
    uint32_t hd0 = hbuf[p][ln];                 // lane i holds h-dword i
    uint32_t hd1 = hbuf[p][64 + k32];           // lane i holds h-dword 64+i (i<32)

    // publish h(t-1) to ring (values already in hd0/hd1)
    if (l < 2 && t > t0) {
      int row = t - 1 - t0;
      if (tid < 64)       hrb[(size_t)row*96 + tid] = hd0;
      else if (tid < 96)  hrb[(size_t)row*96 + tid] = hd1;
    }

    // two gate rows of the SAME h-element: bias + gx + W_hh . h
    // (readlane SGPR broadcast shared by both rows; even/odd dword chains
    //  keep the summation order of the previous kernel)
    float aA0 = biasA + (float)__builtin_bit_cast(_Float16, gxA);
    float aB0 = biasB + (float)__builtin_bit_cast(_Float16, gxB);
    float aA1 = 0.f, aB1 = 0.f;
    #pragma unroll
    for (int k = 0; k < 64; k += 2) {
      uint32_t s0 = (uint32_t)__builtin_amdgcn_readlane((int)hd0, k);
      uint32_t s1 = (uint32_t)__builtin_amdgcn_readlane((int)hd0, k + 1);
      aA0 = dot2(wA[k],     s0, aA0);
      aB0 = dot2(wB[k],     s0, aB0);
      aA1 = dot2(wA[k + 1], s1, aA1);
      aB1 = dot2(wB[k + 1], s1, aB1);
    }
    #pragma unroll
    for (int k = 0; k < 20; k += 2) {
      uint32_t s0 = (uint32_t)__builtin_amdgcn_readlane((int)hd1, k);
      uint32_t s1 = (uint32_t)__builtin_amdgcn_readlane((int)hd1, k + 1);
      aA0 = dot2(wA[64 + k],     s0, aA0);
      aB0 = dot2(wB[64 + k],     s0, aB0);
      aA1 = dot2(wA[64 + k + 1], s1, aA1);
      aB1 = dot2(wB[64 + k + 1], s1, aB1);
    }
    float gA = aA0 + aA1;
    float gB = aB0 + aB1;

    // prefetch next gx (hidden under the swap/update)
    if (t + 1 < t1) {
      gxA = gxb[(size_t)(t + 1 - t0)*GG + rA];
      gxB = gxb[(size_t)(t + 1 - t0)*GG + rB];
    }

    // exchange the other half's two gates within the wave
    float oA = __shfl_xor(gA, 32, 64);
    float oB = __shfl_xor(gB, 32, 64);
    float gi = hf ? oA : gA;
    float gf = hf ? oB : gB;
    float gg = hf ? gA : oA;
    float go = hf ? gB : oB;

    // cell update, all lanes in parallel (redundant across halves)
    cst = sigmf(gf)*cst + sigmf(gi)*tanhf_(gg);
    float hv = sigmf(go)*tanhf_(cst);
    if (valid && hf == 0) {
      _Float16 h16 = (_Float16)hv;
      ((uint16_t*)hbuf[p ^ 1])[j] = __builtin_bit_cast(uint16_t, h16);
    }
    __syncthreads();                            // new h (buf p^1) visible
    p ^= 1;
  }

  // final publish of h(t1-1) + persist state
  {
    uint32_t v = (tid < 96) ? hbuf[p][tid] : 0u;
    if (l < 2 && tid < 96) hrb[(size_t)(t1 - 1 - t0)*96 + tid] = v;
    if (tid < 96) state_h[(l*BB + b)*96 + tid] = v;
    if (valid && hf == 0) state_c[(l*BB + b)*HH + j] = cst;
  }
}

// ---------------------------------------------------------------------------
// FC epilogue on layer-2 final hidden state
// ---------------------------------------------------------------------------
__global__ void kfc(const float* fcw, const float* fcb,
                    const uint32_t* state_h, float* out) {
  int b = blockIdx.x, o = threadIdx.x;
  if (o >= 7) return;
  const uint16_t* h16 = (const uint16_t*)(state_h + (size_t)(2*BB + b)*96);
  float s = fcb[o];
  for (int m = 0; m < HH; ++m) {
    _Float16 hv = __builtin_bit_cast(_Float16, h16[m]);
    s += fcw[o*HH + m] * (float)hv;
  }
  out[b*7 + o] = s;
}

// ---------------------------------------------------------------------------
extern "C" void kernel_launch(void* const* d_in, const int* in_sizes, int n_in,
                              void* d_out, int out_size, void* d_ws, size_t ws_size,
                              hipStream_t stream) {
  const float* x      = (const float*)d_in[0];
  const int*  lengths = (const int*)  d_in[1];
  const float* wih0   = (const float*)d_in[2];
  const float* whh0   = (const float*)d_in[3];
  const float* b0     = (const float*)d_in[4];
  const float* wih1   = (const float*)d_in[5];
  const float* whh1   = (const float*)d_in[6];
  const float* b1     = (const float*)d_in[7];
  const float* wih2   = (const float*)d_in[8];
  const float* whh2   = (const float*)d_in[9];
  const float* b2     = (const float*)d_in[10];
  const float* fcw    = (const float*)d_in[11];
  const float* fcb    = (const float*)d_in[12];

  if (ws_size < (size_t)WS_TOTAL_B) return;     // loud, clean failure

  char* ws = (char*)d_ws;
  _Float16* wih16 = (_Float16*)(ws + OFF_WIH_B);
  _Float16* whh16 = (_Float16*)(ws + OFF_WHH_B);
  uint16_t* gxw   = (uint16_t*)(ws + OFF_GX_B);
  uint32_t* hrw   = (uint32_t*)(ws + OFF_HR_B);
  float*    scw   = (float*)   (ws + OFF_SC_B);
  uint32_t* shw   = (uint32_t*)(ws + OFF_SH_B);

  hipLaunchKernelGGL(kprep_w, dim3((3*GG*192 + 255)/256), dim3(256), 0, stream,
                     wih0, whh0, wih1, whh1, wih2, whh2, wih16, whh16);

  for (int i = 0; i < NCH + 2; ++i) {
    hipLaunchKernelGGL(kgemm, dim3(192), dim3(256), 0, stream,
                       i, lengths, x, (const uint32_t*)wih16, hrw, gxw);
    hipLaunchKernelGGL(krec, dim3(192), dim3(384), 0, stream,
                       i, lengths, b0, b1, b2, (const uint32_t*)whh16,
                       (const uint16_t*)gxw, hrw, scw, shw);
  }

  hipLaunchKernelGGL(kfc, dim3(64), dim3(64), 0, stream,
                     fcw, fcb, shw, (float*)d_out);
}